// Round 8
// baseline (470.775 us; speedup 1.0000x reference)
//
#include <hip/hip_runtime.h>
#include <hip/hip_bf16.h>
#include <math.h>

#define B_       2
#define L_       4096
#define DIM_     1024
#define DINNER_  2048
#define DSTATE_  64
#define NH_      32
#define HD_      64
#define CONVDIM_ 2176
#define DIP_     4256
#define M_       (B_*L_)   // 8192
#define XRW_     2208      // xr row width: xBC raw (2176) + dt_raw (32)
#define NC_      64        // chunks (L/64)

typedef __attribute__((ext_vector_type(8))) short short8;
typedef __attribute__((ext_vector_type(4))) float floatx4;
typedef __hip_bfloat16 bf16;

__device__ __forceinline__ float bf2f(unsigned short u) {
    unsigned int v = ((unsigned int)u) << 16;
    return __builtin_bit_cast(float, v);
}
__device__ __forceinline__ unsigned short f2bf(float f) {
    unsigned int x = __builtin_bit_cast(unsigned int, f);
    unsigned int lsb = (x >> 16) & 1u;
    x += 0x7fffu + lsb;
    return (unsigned short)(x >> 16);
}
__device__ __forceinline__ void storeo(bf16* p, float v) {
    *reinterpret_cast<unsigned short*>(p) = f2bf(v);
}
__device__ __forceinline__ void storeo(float* p, float v) { *p = v; }

__device__ __forceinline__ void gl2lds16(const bf16* g, short* lds) {
    __builtin_amdgcn_global_load_lds(
        (const __attribute__((address_space(1))) void*)g,
        (__attribute__((address_space(3))) void*)lds, 16, 0, 0);
}

// ---------------------------------------------------------------------------
// Merged input cast: X (nb1 blocks) then Wip. 8 f32->bf16 per thread.
// ---------------------------------------------------------------------------
__global__ __launch_bounds__(256) void cast2_k(
    const float* __restrict__ s1, bf16* __restrict__ d1,
    const float* __restrict__ s2, bf16* __restrict__ d2, int nb1)
{
    const float* src;
    bf16* dst;
    size_t i0;
    if ((int)blockIdx.x < nb1) {
        src = s1; dst = d1;
        i0 = ((size_t)blockIdx.x * 256 + threadIdx.x) * 8;
    } else {
        src = s2; dst = d2;
        i0 = ((size_t)(blockIdx.x - nb1) * 256 + threadIdx.x) * 8;
    }
    uint4 a = *reinterpret_cast<const uint4*>(src + i0);
    uint4 b = *reinterpret_cast<const uint4*>(src + i0 + 4);
    unsigned int w0 = (unsigned int)f2bf(__builtin_bit_cast(float, a.x)) |
                      ((unsigned int)f2bf(__builtin_bit_cast(float, a.y)) << 16);
    unsigned int w1 = (unsigned int)f2bf(__builtin_bit_cast(float, a.z)) |
                      ((unsigned int)f2bf(__builtin_bit_cast(float, a.w)) << 16);
    unsigned int w2 = (unsigned int)f2bf(__builtin_bit_cast(float, b.x)) |
                      ((unsigned int)f2bf(__builtin_bit_cast(float, b.y)) << 16);
    unsigned int w3 = (unsigned int)f2bf(__builtin_bit_cast(float, b.z)) |
                      ((unsigned int)f2bf(__builtin_bit_cast(float, b.w)) << 16);
    *reinterpret_cast<uint4*>(reinterpret_cast<unsigned short*>(dst) + i0) =
        make_uint4(w0, w1, w2, w3);
}

// ---------------------------------------------------------------------------
// Merged weight prep: blocks [0,512): WopT[p,d] = bf16(Wop[d,p]) via 64x64
// LDS transpose tiles; blocks [512,1536): Wthb = bf16(Wth) elementwise.
// ---------------------------------------------------------------------------
__global__ __launch_bounds__(256) void wprep_k(
    const float* __restrict__ Wop, bf16* __restrict__ WopT,
    const float* __restrict__ Wth, bf16* __restrict__ Wthb)
{
    __shared__ unsigned short t[64][72];
    if (blockIdx.x < 512) {
        // transpose 1024x2048 -> 2048x1024
        const int R = 1024, C = 2048;
        int nct = C >> 6;
        int r0 = ((int)blockIdx.x / nct) << 6;
        int c0 = ((int)blockIdx.x % nct) << 6;
        int tr = threadIdx.x >> 2;
        int tc = (threadIdx.x & 3) << 4;
        const float* s = Wop + (size_t)(r0 + tr) * C + c0 + tc;
#pragma unroll
        for (int k = 0; k < 16; k += 4) {
            float4 v = *reinterpret_cast<const float4*>(s + k);
            t[tr][tc + k + 0] = f2bf(v.x);
            t[tr][tc + k + 1] = f2bf(v.y);
            t[tr][tc + k + 2] = f2bf(v.z);
            t[tr][tc + k + 3] = f2bf(v.w);
        }
        __syncthreads();
        unsigned short* d = (unsigned short*)WopT + (size_t)(c0 + tr) * R + r0 + tc;
        unsigned int ww[8];
#pragma unroll
        for (int q = 0; q < 8; q++)
            ww[q] = (unsigned int)t[tc + 2*q][tr] | ((unsigned int)t[tc + 2*q + 1][tr] << 16);
        *reinterpret_cast<uint4*>(d)     = make_uint4(ww[0], ww[1], ww[2], ww[3]);
        *reinterpret_cast<uint4*>(d + 8) = make_uint4(ww[4], ww[5], ww[6], ww[7]);
    } else {
        size_t i0 = ((size_t)(blockIdx.x - 512) * 256 + threadIdx.x) * 8;
        uint4 a = *reinterpret_cast<const uint4*>(Wth + i0);
        uint4 b = *reinterpret_cast<const uint4*>(Wth + i0 + 4);
        unsigned int w0 = (unsigned int)f2bf(__builtin_bit_cast(float, a.x)) |
                          ((unsigned int)f2bf(__builtin_bit_cast(float, a.y)) << 16);
        unsigned int w1 = (unsigned int)f2bf(__builtin_bit_cast(float, a.z)) |
                          ((unsigned int)f2bf(__builtin_bit_cast(float, a.w)) << 16);
        unsigned int w2 = (unsigned int)f2bf(__builtin_bit_cast(float, b.x)) |
                          ((unsigned int)f2bf(__builtin_bit_cast(float, b.y)) << 16);
        unsigned int w3 = (unsigned int)f2bf(__builtin_bit_cast(float, b.z)) |
                          ((unsigned int)f2bf(__builtin_bit_cast(float, b.w)) << 16);
        *reinterpret_cast<uint4*>(reinterpret_cast<unsigned short*>(Wthb) + i0) =
            make_uint4(w0, w1, w2, w3);
    }
}

// ---------------------------------------------------------------------------
// bf16 GEMM, m97 structure, 128x128 tile (proven baseline kernel).
// Used for the small Wc = Wth @ Wop^T weight-product GEMM (256 blocks).
// ---------------------------------------------------------------------------
template <typename TO>
__global__ __launch_bounds__(256) void gemm_bt16(
    const bf16* __restrict__ A, const bf16* __restrict__ W,
    TO* __restrict__ outA, TO* __restrict__ outB,
    int M, int N, int K, int split, int strideA, int strideB)
{
    __shared__ short As[128*64];
    __shared__ short Ws[128*64];
    const int tid  = threadIdx.x;
    const int m0   = blockIdx.y * 128;
    const int n0   = blockIdx.x * 128;
    const int wave = tid >> 6;
    const int lane = tid & 63;
    const int wm   = (wave >> 1) * 64;
    const int wn   = (wave & 1) * 64;
    const int ln   = lane & 15;
    const int quad = lane >> 4;
    const int lr   = lane >> 3;
    const int lc   = (lane & 7) * 8;

    floatx4 acc[4][4];
#pragma unroll
    for (int i = 0; i < 4; i++)
#pragma unroll
        for (int j = 0; j < 4; j++) acc[i][j] = (floatx4){0.f, 0.f, 0.f, 0.f};

    for (int k0 = 0; k0 < K; k0 += 64) {
#pragma unroll
        for (int it = 0; it < 4; it++) {
            int ig = wave * 4 + it;
            gl2lds16(A + (size_t)(m0 + ig * 8 + lr) * K + k0 + lc, &As[ig * 512]);
            gl2lds16(W + (size_t)(n0 + ig * 8 + lr) * K + k0 + lc, &Ws[ig * 512]);
        }
        __syncthreads();
#pragma unroll
        for (int kk = 0; kk < 64; kk += 32) {
            short8 af[4], bfv[4];
#pragma unroll
            for (int i = 0; i < 4; i++)
                af[i] = *reinterpret_cast<const short8*>(&As[(wm + i * 16 + ln) * 64 + kk + quad * 8]);
#pragma unroll
            for (int j = 0; j < 4; j++)
                bfv[j] = *reinterpret_cast<const short8*>(&Ws[(wn + j * 16 + ln) * 64 + kk + quad * 8]);
#pragma unroll
            for (int i = 0; i < 4; i++)
#pragma unroll
                for (int j = 0; j < 4; j++)
                    acc[i][j] = __builtin_amdgcn_mfma_f32_16x16x32_bf16(af[i], bfv[j], acc[i][j], 0, 0, 0);
        }
        __syncthreads();
    }

#pragma unroll
    for (int i = 0; i < 4; i++)
#pragma unroll
        for (int j = 0; j < 4; j++)
#pragma unroll
            for (int r = 0; r < 4; r++) {
                int grow = m0 + wm + i * 16 + quad * 4 + r;
                int gcol = n0 + wn + j * 16 + ln;
                if (gcol < N) {
                    if (gcol < split)
                        storeo(outA + (size_t)grow * strideA + gcol, acc[i][j][r]);
                    else
                        storeo(outB + (size_t)grow * strideB + (gcol - split), acc[i][j][r]);
                }
            }
}

// ---------------------------------------------------------------------------
// bf16 GEMM, 256x256 tile, 4-phase-per-K-tile schedule with NEVER-DRAIN
// counted vmcnt (audited; see derivation in round log).
//  - 512 threads = 8 waves 2(M)x4(N); per-wave output 128x64. LDS 128 KiB
//    double-buffered; 3-bit XOR swizzle ((row&7)<<4) via inverse-swizzled
//    global source + swizzled ds_read (0 bank conflicts, verified).
//  - Quadrant order (0,0)->(0,1)->(1,1)->(1,0). Block-wide retirement:
//    B-halves fully read by P1-end barrier, A-halves by P2-end barrier
//    (every ds_read is MFMA-consumed before its phase's trailing barrier).
//  - Staging (1 half-tile = 2 gl2lds/thread per phase):
//      P0: A-half-0 of tile t+1 -> dead buffer (WAR-trivial)
//      P1: A-half-1 of tile t+1 -> dead buffer
//      P2: B-half-0 of tile t+2 -> CURRENT buffer B region (retired P1-end)
//      P3: B-half-1 of tile t+2 -> same
//  - One vmcnt(4) per tile at P3: allows the 2 newest half-tiles (t+2's B)
//    in flight, confirms ALL of tile t+1 (A staged this tile, B staged last
//    tile) -- and is followed by TWO barriers before any t+1 read (the R4
//    invariant). Main loop never drains to 0.
//  - Prologue: stage K0 (4 halves) + K1's B halves; vmcnt(4); barrier.
// ---------------------------------------------------------------------------
template <typename TO>
__global__ __launch_bounds__(512, 2) void gemm256(
    const bf16* __restrict__ Ag, const bf16* __restrict__ Wg,
    TO* __restrict__ outA, TO* __restrict__ outB,
    int M, int N, int K, int split, int strideA, int strideB, int nbx)
{
    __shared__ short lds[65536];   // 128 KiB: A at [0,32768), B at [32768,65536)

    const int tid  = threadIdx.x;
    const int wave = tid >> 6;
    const int lane = tid & 63;
    const int ln   = lane & 15;
    const int quad = lane >> 4;
    const int wr   = wave >> 2;    // 0..1 (M)
    const int wc   = wave & 3;     // 0..3 (N)
    const int bh   = wc >> 1;      // B half this wave reads
    const int wcl  = wc & 1;
    const int xorv = (ln & 7) << 4;   // read-side swizzle (3 row bits)

    // XCD-aware bijective block swizzle (nwg % 8 == 0 for all our launches)
    int nwg  = gridDim.x;
    int orig = blockIdx.x;
    int wg   = ((nwg & 7) == 0) ? ((orig & 7) * (nwg >> 3) + (orig >> 3)) : orig;
    const int bx = wg % nbx;
    const int by = wg / nbx;
    const int m0 = by * 256;
    const int n0 = bx * 256;

    // staging: thread covers linear (physical) 16B chunks of each 16KB
    // half-tile; fetch the global element at the swizzle-inverse (logical)
    // offset so that swizzled reads see a consistent layout.
    int lo0 = tid * 16;
    int lo1 = 8192 + tid * 16;
    int so0 = lo0 ^ (((lo0 >> 7) & 7) << 4);
    int so1 = lo1 ^ (((lo1 >> 7) & 7) << 4);
    const int srow0 = so0 >> 7, scol0 = (so0 & 127) >> 1;
    const int srow1 = so1 >> 7, scol1 = (so1 & 127) >> 1;

#define STG_A(bufb, h, kc) do {                                               \
    short* dst_ = &lds[((bufb)*2 + (h)) * 8192 + wave * 512];                 \
    gl2lds16(Ag + (size_t)(m0 + (h)*128 + srow0) * K + (kc) + scol0, dst_);   \
    gl2lds16(Ag + (size_t)(m0 + (h)*128 + srow1) * K + (kc) + scol1, dst_ + 4096); \
} while (0)
#define STG_B(bufb, h, kc) do {                                               \
    short* dst_ = &lds[32768 + ((bufb)*2 + (h)) * 8192 + wave * 512];         \
    gl2lds16(Wg + (size_t)(n0 + (h)*128 + srow0) * K + (kc) + scol0, dst_);   \
    gl2lds16(Wg + (size_t)(n0 + (h)*128 + srow1) * K + (kc) + scol1, dst_ + 4096); \
} while (0)

#define RD_A(qi) do {                                                         \
    const char* Ab_ = (const char*)&lds[(cur*2 + wr) * 8192];                 \
    _Pragma("unroll") for (int i = 0; i < 4; i++)                             \
    _Pragma("unroll") for (int ks = 0; ks < 2; ks++)                          \
        af[i][ks] = *reinterpret_cast<const short8*>(                         \
            Ab_ + ((((qi)*64 + i*16 + ln)*128 + ks*64 + quad*16) ^ xorv));    \
} while (0)
#define RD_B(qj, BV) do {                                                     \
    const char* Bb_ = (const char*)&lds[32768 + (cur*2 + bh) * 8192];         \
    _Pragma("unroll") for (int j = 0; j < 2; j++)                             \
    _Pragma("unroll") for (int ks = 0; ks < 2; ks++)                          \
        BV[j][ks] = *reinterpret_cast<const short8*>(                         \
            Bb_ + (((wcl*64 + (qj)*32 + j*16 + ln)*128 + ks*64 + quad*16) ^ xorv)); \
} while (0)

#define MMA(qi, qj, BV) do {                                                  \
    __builtin_amdgcn_s_setprio(1);                                            \
    _Pragma("unroll") for (int i = 0; i < 4; i++)                             \
    _Pragma("unroll") for (int j = 0; j < 2; j++)                             \
    _Pragma("unroll") for (int ks = 0; ks < 2; ks++)                          \
        acc[(qi)*4+i][(qj)*2+j] = __builtin_amdgcn_mfma_f32_16x16x32_bf16(    \
            af[i][ks], BV[j][ks], acc[(qi)*4+i][(qj)*2+j], 0, 0, 0);          \
    __builtin_amdgcn_s_setprio(0);                                            \
} while (0)

    floatx4 acc[8][4];
#pragma unroll
    for (int i = 0; i < 8; i++)
#pragma unroll
        for (int j = 0; j < 4; j++) acc[i][j] = (floatx4){0.f, 0.f, 0.f, 0.f};

    const int NT = K >> 6;

    // prologue: stage K0 fully + K1's B halves; counted wait; barrier.
    STG_A(0, 0, 0); STG_A(0, 1, 0);
    STG_B(0, 0, 0); STG_B(0, 1, 0);
    if (NT > 1) {
        STG_B(1, 0, 64); STG_B(1, 1, 64);
        asm volatile("s_waitcnt vmcnt(4)" ::: "memory");
    } else {
        asm volatile("s_waitcnt vmcnt(0)" ::: "memory");
    }
    __builtin_amdgcn_s_barrier();
    __builtin_amdgcn_sched_barrier(0);

    short8 af[4][2], bf0[2][2], bf1[2][2];

    for (int t = 0; t < NT; ++t) {
        const int cur = t & 1, oth = cur ^ 1;
        const int kc1 = (t + 1) << 6;
        const int kc2 = (t + 2) << 6;

        // ---- P0: stage A0(t+1) -> dead buf; read A(0), B(0) ----
        if (t + 1 < NT) STG_A(oth, 0, kc1);
        RD_A(0); RD_B(0, bf0);
        __builtin_amdgcn_s_barrier();
        MMA(0, 0, bf0);
        __builtin_amdgcn_s_barrier();

        // ---- P1: stage A1(t+1) -> dead buf; read B(1) ----
        if (t + 1 < NT) STG_A(oth, 1, kc1);
        RD_B(1, bf1);
        __builtin_amdgcn_s_barrier();
        MMA(0, 1, bf1);
        __builtin_amdgcn_s_barrier();
        // B-halves of cur fully retired here (block-wide).

        // ---- P2: stage B0(t+2) -> cur buf B region; read A(1) ----
        if (t + 2 < NT) STG_B(cur, 0, kc2);
        RD_A(1);
        __builtin_amdgcn_s_barrier();
        MMA(1, 1, bf1);
        __builtin_amdgcn_s_barrier();
        // A-halves of cur fully retired here.

        // ---- P3: stage B1(t+2); counted wait confirming tile t+1 ----
        if (t + 2 < NT) {
            STG_B(cur, 1, kc2);
            asm volatile("s_waitcnt vmcnt(4)" ::: "memory");
        } else if (t + 1 < NT) {
            asm volatile("s_waitcnt vmcnt(0)" ::: "memory");
        }
        __builtin_amdgcn_s_barrier();
        MMA(1, 0, bf0);
        __builtin_amdgcn_s_barrier();
        __builtin_amdgcn_sched_barrier(0);
    }

#undef STG_A
#undef STG_B
#undef RD_A
#undef RD_B
#undef MMA

    // epilogue: split store
#pragma unroll
    for (int qi = 0; qi < 2; qi++)
#pragma unroll
    for (int i = 0; i < 4; i++)
#pragma unroll
    for (int qj = 0; qj < 2; qj++)
#pragma unroll
    for (int j = 0; j < 2; j++)
#pragma unroll
    for (int r = 0; r < 4; r++) {
        int grow = m0 + wr*128 + qi*64 + i*16 + quad*4 + r;
        int gcol = n0 + wc*64 + qj*32 + j*16 + ln;
        float v = acc[qi*4+i][qj*2+j][r];
        if (gcol < N) {
            if (gcol < split)
                storeo(outA + (size_t)grow * strideA + gcol, v);
            else
                storeo(outB + (size_t)grow * strideB + (gcol - split), v);
        }
    }
}

// ---------------------------------------------------------------------------
// Conv+bias+silu over 2176 xBC channels PLUS softplus(dt) — merged kernel.
// 276 groups of 8 per row: groups [0,272) conv, [272,276) dt.
// Grid: M*276/256 = 8832.
// ---------------------------------------------------------------------------
__global__ __launch_bounds__(256) void conv_dt_k(
    const bf16* __restrict__ xr, const float* __restrict__ cw,
    const float* __restrict__ cb, const float* __restrict__ dtb,
    bf16* __restrict__ xc, float* __restrict__ dtf)
{
    int idx = blockIdx.x * 256 + threadIdx.x;
    int row = idx / 276;
    int g   = idx - row * 276;
    const unsigned short* xru = (const unsigned short*)xr;

    if (g >= 272) {
        int h0 = (g - 272) * 8;
        uint4 rv = *reinterpret_cast<const uint4*>(xru + (size_t)row * XRW_ + 2176 + h0);
        const unsigned int* w = &rv.x;
        float o[8];
#pragma unroll
        for (int k = 0; k < 8; k++) {
            unsigned short u = (k & 1) ? (unsigned short)(w[k >> 1] >> 16)
                                       : (unsigned short)(w[k >> 1] & 0xffffu);
            float v = bf2f(u) + dtb[h0 + k];
            o[k] = fmaxf(v, 0.f) + log1pf(__expf(-fabsf(v)));
        }
        *reinterpret_cast<float4*>(&dtf[(size_t)row * NH_ + h0]) =
            make_float4(o[0], o[1], o[2], o[3]);
        *reinterpret_cast<float4*>(&dtf[(size_t)row * NH_ + h0 + 4]) =
            make_float4(o[4], o[5], o[6], o[7]);
        return;
    }

    int ch0 = g * 8;
    int t   = row & (L_ - 1);
    uint4 rv[4];
#pragma unroll
    for (int j = 0; j < 4; j++) {
        rv[j] = make_uint4(0u, 0u, 0u, 0u);
        if (t + j - 3 >= 0)
            rv[j] = *reinterpret_cast<const uint4*>(xru + (size_t)(row + j - 3) * XRW_ + ch0);
    }
    unsigned int ow[4];
#pragma unroll
    for (int pair = 0; pair < 4; pair++) {
        unsigned short o2[2];
#pragma unroll
        for (int k = 0; k < 2; k++) {
            int cc = pair * 2 + k;
            float a = cb[ch0 + cc];
#pragma unroll
            for (int j = 0; j < 4; j++) {
                unsigned int w32 = (&rv[j].x)[cc >> 1];
                unsigned short u = (cc & 1) ? (unsigned short)(w32 >> 16)
                                            : (unsigned short)(w32 & 0xffffu);
                a = fmaf(bf2f(u), cw[(ch0 + cc) * 4 + j], a);
            }
            o2[k] = f2bf(a / (1.f + __expf(-a)));
        }
        ow[pair] = (unsigned int)o2[0] | ((unsigned int)o2[1] << 16);
    }
    *reinterpret_cast<uint4*>((unsigned short*)xc + (size_t)row * CONVDIM_ + ch0) =
        make_uint4(ow[0], ow[1], ow[2], ow[3]);
}

// ---------------------------------------------------------------------------
// Pass A (slim): per (b,chunk,h): stage pre-activated x/B/C, 3 MFMA GEMMs.
// blockIdx.x = ((b*64+c)*32+h). Wave-parallel prefix scan for cums.
// ---------------------------------------------------------------------------
__global__ __launch_bounds__(256) void chunk_intra_k(
    const bf16* __restrict__ xc, const float* __restrict__ dtf,
    const float* __restrict__ A_log, const float* __restrict__ Dp,
    bf16* __restrict__ Yg, float* __restrict__ Sg, float* __restrict__ Eg)
{
    __shared__ short Bst[64*72];
    __shared__ short Cst[64*72];
    __shared__ short xsM[64*72];   // x staging, then reused as masked M
    __shared__ short xT [64*72];
    __shared__ short BwT[64*72];
    __shared__ float dts[64], cums[64], wS[64];

    const int tid  = threadIdx.x;
    const int bid  = blockIdx.x;
    const int h    = bid & 31;
    const int bc   = bid >> 5;
    const int c    = bc & 63;
    const int b    = bc >> 6;
    const int xch0 = h * 64;
    const unsigned short* xcu = (const unsigned short*)xc;

    const float Ah = -__expf(A_log[h]);
    const float Dh = Dp[h];

    // stage B / C / x tiles (rows s = 0..63)
    for (int q = tid; q < 1536; q += 256) {
        int sel = q >> 9;              // 0:B 1:C 2:x
        int qq  = q & 511;
        int r = qq >> 3, c8 = (qq & 7) * 8;
        size_t ro = (size_t)(b * L_ + c * 64 + r) * CONVDIM_;
        if (sel == 0)
            *reinterpret_cast<uint4*>(&Bst[r*72 + c8]) =
                *reinterpret_cast<const uint4*>(xcu + ro + 2048 + c8);
        else if (sel == 1)
            *reinterpret_cast<uint4*>(&Cst[r*72 + c8]) =
                *reinterpret_cast<const uint4*>(xcu + ro + 2112 + c8);
        else
            *reinterpret_cast<uint4*>(&xsM[r*72 + c8]) =
                *reinterpret_cast<const uint4*>(xcu + ro + xch0 + c8);
    }
    if (tid < 64) dts[tid] = dtf[(size_t)(b * L_ + c * 64 + tid) * NH_ + h];
    __syncthreads();

    // wave-parallel inclusive prefix scan of dts*Ah (wave 0, 6 shfl steps)
    if (tid < 64) {
        float v = dts[tid] * Ah;
#pragma unroll
        for (int o = 1; o < 64; o <<= 1) {
            float u = __shfl_up(v, o, 64);
            if (tid >= o) v += u;
        }
        cums[tid] = v;
    }
    __syncthreads();
    if (tid < 64) wS[tid] = __expf(cums[63] - cums[tid]) * dts[tid];
    if (tid == 0) Eg[bid] = __expf(cums[63]);
    __syncthreads();

    // transposes: xT[p][s] = x[s][p]; BwT[n][s] = B[s][n]*wS[s]
    for (int q = tid; q < 4096; q += 256) {
        int s = q & 63, ch = q >> 6;
        xT [ch*72 + s] = xsM[s*72 + ch];
        BwT[ch*72 + s] = (short)f2bf(bf2f((unsigned short)Bst[s*72 + ch]) * wS[s]);
    }
    __syncthreads();

    const int wave = tid >> 6, lane = tid & 63;
    const int ln = lane & 15, quad = lane >> 4;
    const int wm = (wave >> 1) * 32, wn = (wave & 1) * 32;

    // --- G = C · B^T ---
    floatx4 accG[2][2];
#pragma unroll
    for (int i = 0; i < 2; i++)
#pragma unroll
        for (int j = 0; j < 2; j++) accG[i][j] = (floatx4){0.f,0.f,0.f,0.f};
#pragma unroll
    for (int kk = 0; kk < 64; kk += 32) {
        short8 af[2], bfv[2];
#pragma unroll
        for (int i = 0; i < 2; i++)
            af[i] = *reinterpret_cast<const short8*>(&Cst[(wm + i*16 + ln)*72 + kk + quad*8]);
#pragma unroll
        for (int j = 0; j < 2; j++)
            bfv[j] = *reinterpret_cast<const short8*>(&Bst[(wn + j*16 + ln)*72 + kk + quad*8]);
#pragma unroll
        for (int i = 0; i < 2; i++)
#pragma unroll
            for (int j = 0; j < 2; j++)
                accG[i][j] = __builtin_amdgcn_mfma_f32_16x16x32_bf16(af[i], bfv[j], accG[i][j], 0,0,0);
    }
    __syncthreads();   // all xsM staging reads done -> safe to overwrite
#pragma unroll
    for (int i = 0; i < 2; i++)
#pragma unroll
        for (int j = 0; j < 2; j++)
#pragma unroll
            for (int r = 0; r < 4; r++) {
                int t = wm + i*16 + quad*4 + r;
                int s = wn + j*16 + ln;
                float v = (s <= t) ? __expf(cums[t] - cums[s]) * dts[s] * accG[i][j][r] : 0.f;
                xsM[t*72 + s] = (short)f2bf(v);
            }
    __syncthreads();

    // --- Yintra = M · xT^T + D*x ---
    floatx4 accY[2][2];
#pragma unroll
    for (int i = 0; i < 2; i++)
#pragma unroll
        for (int j = 0; j < 2; j++) accY[i][j] = (floatx4){0.f,0.f,0.f,0.f};
#pragma unroll
    for (int kk = 0; kk < 64; kk += 32) {
        short8 af[2], bfv[2];
#pragma unroll
        for (int i = 0; i < 2; i++)
            af[i] = *reinterpret_cast<const short8*>(&xsM[(wm + i*16 + ln)*72 + kk + quad*8]);
#pragma unroll
        for (int j = 0; j < 2; j++)
            bfv[j] = *reinterpret_cast<const short8*>(&xT[(wn + j*16 + ln)*72 + kk + quad*8]);
#pragma unroll
        for (int i = 0; i < 2; i++)
#pragma unroll
            for (int j = 0; j < 2; j++)
                accY[i][j] = __builtin_amdgcn_mfma_f32_16x16x32_bf16(af[i], bfv[j], accY[i][j], 0,0,0);
    }
    unsigned short* Yu = (unsigned short*)Yg;
#pragma unroll
    for (int i = 0; i < 2; i++)
#pragma unroll
        for (int j = 0; j < 2; j++)
#pragma unroll
            for (int r = 0; r < 4; r++) {
                int t = wm + i*16 + quad*4 + r;
                int p = wn + j*16 + ln;
                float yv = accY[i][j][r] + Dh * bf2f((unsigned short)xT[p*72 + t]);
                Yu[(size_t)(b*L_ + c*64 + t)*DINNER_ + xch0 + p] = f2bf(yv);
            }

    // --- S^T = xT · BwT^T ---
    floatx4 accS[2][2];
#pragma unroll
    for (int i = 0; i < 2; i++)
#pragma unroll
        for (int j = 0; j < 2; j++) accS[i][j] = (floatx4){0.f,0.f,0.f,0.f};
#pragma unroll
    for (int kk = 0; kk < 64; kk += 32) {
        short8 af[2], bfv[2];
#pragma unroll
        for (int i = 0; i < 2; i++)
            af[i] = *reinterpret_cast<const short8*>(&xT[(wm + i*16 + ln)*72 + kk + quad*8]);
#pragma unroll
        for (int j = 0; j < 2; j++)
            bfv[j] = *reinterpret_cast<const short8*>(&BwT[(wn + j*16 + ln)*72 + kk + quad*8]);
#pragma unroll
        for (int i = 0; i < 2; i++)
#pragma unroll
            for (int j = 0; j < 2; j++)
                accS[i][j] = __builtin_amdgcn_mfma_f32_16x16x32_bf16(af[i], bfv[j], accS[i][j], 0,0,0);
    }
#pragma unroll
    for (int i = 0; i < 2; i++)
#pragma unroll
        for (int j = 0; j < 2; j++)
#pragma unroll
            for (int r = 0; r < 4; r++) {
                int p = wm + i*16 + quad*4 + r;
                int n = wn + j*16 + ln;
                Sg[(size_t)bid * 4096 + p*64 + n] = accS[i][j][r];
            }
}

// ---------------------------------------------------------------------------
// Pass B: prefix over chunks (unchanged).
// ---------------------------------------------------------------------------
__global__ __launch_bounds__(256) void chunk_state_k(
    float* __restrict__ Sg, const float* __restrict__ Eg)
{
    int g  = blockIdx.x * 1024 + threadIdx.x * 4;
    int bh = g >> 12;
    int b  = bh >> 5, h = bh & 31;
    int e  = g & 4095;
    float4 run = make_float4(0.f, 0.f, 0.f, 0.f);
    for (int c = 0; c < NC_; c++) {
        int bid = (b * 64 + c) * 32 + h;
        size_t idx = (size_t)bid * 4096 + e;
        float4 s = *reinterpret_cast<float4*>(&Sg[idx]);
        float  E = Eg[bid];
        *reinterpret_cast<float4*>(&Sg[idx]) = run;
        run.x = run.x * E + s.x;
        run.y = run.y * E + s.y;
        run.z = run.z * E + s.z;
        run.w = run.w * E + s.w;
    }
}

// ---------------------------------------------------------------------------
// Pass C: Y += e^{cum[t]} * C·hprev^T. Wave-parallel prefix scan.
// ---------------------------------------------------------------------------
__global__ __launch_bounds__(256) void chunk_inter_k(
    const bf16* __restrict__ xc, const float* __restrict__ Sg,
    const float* __restrict__ dtf, const float* __restrict__ A_log,
    bf16* __restrict__ Yg)
{
    __shared__ short Cst[64*72];
    __shared__ short hpT[64*72];
    __shared__ float dts[64], wcumL[64];

    const int tid = threadIdx.x;
    const int bid = blockIdx.x;
    const int h   = bid & 31;
    const int bc  = bid >> 5;
    const int c   = bc & 63;
    const int b   = bc >> 6;
    const unsigned short* xcu = (const unsigned short*)xc;

    const float Ah = -__expf(A_log[h]);

    for (int q = tid; q < 512; q += 256) {
        int r = q >> 3, c8 = (q & 7) * 8;
        *reinterpret_cast<uint4*>(&Cst[r*72 + c8]) =
            *reinterpret_cast<const uint4*>(xcu + (size_t)(b*L_ + c*64 + r)*CONVDIM_ + 2112 + c8);
    }
    for (int q = tid; q < 1024; q += 256) {
        int p = q >> 4, n4 = (q & 15) * 4;
        float4 v = *reinterpret_cast<const float4*>(&Sg[(size_t)bid * 4096 + p*64 + n4]);
        unsigned int lo = (unsigned int)f2bf(v.x) | ((unsigned int)f2bf(v.y) << 16);
        unsigned int hi = (unsigned int)f2bf(v.z) | ((unsigned int)f2bf(v.w) << 16);
        *reinterpret_cast<uint2*>(&hpT[p*72 + n4]) = make_uint2(lo, hi);
    }
    if (tid < 64) dts[tid] = dtf[(size_t)(b*L_ + c*64 + tid) * NH_ + h];
    __syncthreads();
    if (tid < 64) {
        float v = dts[tid] * Ah;
#pragma unroll
        for (int o = 1; o < 64; o <<= 1) {
            float u = __shfl_up(v, o, 64);
            if (tid >= o) v += u;
        }
        wcumL[tid] = __expf(v);
    }
    __syncthreads();

    const int wave = tid >> 6, lane = tid & 63;
    const int ln = lane & 15, quad = lane >> 4;
    const int wm = (wave >> 1) * 32, wn = (wave & 1) * 32;

    floatx4 acc[2][2];
#pragma unroll
    for (int i = 0; i < 2; i++)
#pragma unroll
        for (int j = 0; j < 2; j++) acc[i][j] = (floatx4){0.f,0.f,0.f,0.f};
#pragma unroll
    for (int kk = 0; kk < 64; kk += 32) {
        short8 af[2], bfv[2];
#pragma unroll
        for (int i = 0; i < 2; i++)
            af[i] = *reinterpret_cast<const short8*>(&Cst[(wm + i*16 + ln)*72 + kk + quad*8]);
#pragma unroll
        for (int j = 0; j < 2; j++)
            bfv[j] = *reinterpret_cast<const short8*>(&hpT[(wn + j*16 + ln)*72 + kk + quad*8]);
#pragma unroll
        for (int i = 0; i < 2; i++)
#pragma unroll
            for (int j = 0; j < 2; j++)
                acc[i][j] = __builtin_amdgcn_mfma_f32_16x16x32_bf16(af[i], bfv[j], acc[i][j], 0,0,0);
    }
    unsigned short* Yu = (unsigned short*)Yg;
#pragma unroll
    for (int i = 0; i < 2; i++)
#pragma unroll
        for (int j = 0; j < 2; j++)
#pragma unroll
            for (int r = 0; r < 4; r++) {
                int t = wm + i*16 + quad*4 + r;
                int p = wn + j*16 + ln;
                size_t idx = (size_t)(b*L_ + c*64 + t)*DINNER_ + h*64 + p;
                float yv = bf2f(Yu[idx]) + wcumL[t] * acc[i][j][r];
                Yu[idx] = f2bf(yv);
            }
}

// ---------------------------------------------------------------------------
// gate + RMSNorm (unchanged).
// ---------------------------------------------------------------------------
__global__ __launch_bounds__(256) void gate_norm_k(
    bf16* __restrict__ y, const bf16* __restrict__ zbuf, const float* __restrict__ nw)
{
    __shared__ float red[4];
    int row = blockIdx.x;
    int tid = threadIdx.x;
    unsigned short* yy = (unsigned short*)y;
    const unsigned short* zz = (const unsigned short*)zbuf;

    uint4 yv = *reinterpret_cast<uint4*>(&yy[(size_t)row * DINNER_ + tid * 8]);
    uint4 zv = *reinterpret_cast<const uint4*>(&zz[(size_t)row * DINNER_ + tid * 8]);
    unsigned int yw[4] = {yv.x, yv.y, yv.z, yv.w};
    unsigned int zw[4] = {zv.x, zv.y, zv.z, zv.w};
    float g[8];
    float ss = 0.f;
#pragma unroll
    for (int q = 0; q < 4; q++) {
        float y0 = bf2f((unsigned short)(yw[q] & 0xffffu)), y1 = bf2f((unsigned short)(yw[q] >> 16));
        float z0 = bf2f((unsigned short)(zw[q] & 0xffffu)), z1 = bf2f((unsigned short)(zw[q] >> 16));
        float g0 = y0 * (z0 / (1.f + __expf(-z0)));
        float g1 = y1 * (z1 / (1.f + __expf(-z1)));
        g[q * 2] = g0; g[q * 2 + 1] = g1;
        ss += g0 * g0 + g1 * g1;
    }
#pragma unroll
    for (int o = 1; o < 64; o <<= 1) ss += __shfl_xor(ss, o);
    if ((tid & 63) == 0) red[tid >> 6] = ss;
    __syncthreads();
    float tot = red[0] + red[1] + red[2] + red[3];
    float rinv = rsqrtf(tot * (1.f / DINNER_) + 1e-5f);

    unsigned int ow[4];
#pragma unroll
    for (int q = 0; q < 4; q++) {
        float w0 = nw[tid * 8 + q * 2];
        float w1 = nw[tid * 8 + q * 2 + 1];
        unsigned short o0 = f2bf(g[q * 2] * rinv * w0);
        unsigned short o1 = f2bf(g[q * 2 + 1] * rinv * w1);
        ow[q] = (unsigned int)o0 | ((unsigned int)o1 << 16);
    }
    *reinterpret_cast<uint4*>(&yy[(size_t)row * DINNER_ + tid * 8]) =
        make_uint4(ow[0], ow[1], ow[2], ow[3]);
}

// ---------------------------------------------------------------------------

extern "C" void kernel_launch(void* const* d_in, const int* in_sizes, int n_in,
                              void* d_out, int out_size, void* d_ws, size_t ws_size,
                              hipStream_t stream)
{
    const float* X    = (const float*)d_in[0];
    const float* Wip  = (const float*)d_in[1];
    const float* cw   = (const float*)d_in[2];
    const float* cb   = (const float*)d_in[3];
    const float* dtb  = (const float*)d_in[4];
    const float* Alog = (const float*)d_in[5];
    const float* Dp   = (const float*)d_in[6];
    const float* nw   = (const float*)d_in[7];
    const float* Wop  = (const float*)d_in[8];
    const float* Wth  = (const float*)d_in[9];
    float* out = (float*)d_out;

    // ws layout (peak 106,446,848 B):
    //   [0, 33554432)          zbuf (gemm1->gate); after gate: WopT (4MB) |
    //                          Wthb (4MB) | Wc (8MB) in the dead zbuf region
    //   [33554432, 69730304)   xr (gemm1->conv_dt); then Yg
    //   [69730304, 105381888)  xc (conv_dt->chunk_inter); Xb/Wipb alias
    //                          pre-gemm1
    //   [105381888, 106430464) dtf M x 32 f32
    //   [106430464, 106446848) Eg 4096 f32
    // Sg lives in d_out (dead before the fused HKV gemm overwrites d_out).
    char* ws = (char*)d_ws;
    bf16*  zbuf = (bf16*) (ws);
    bf16*  WopT = (bf16*) (ws);                       // 2048x1024 bf16 (4MB)
    bf16*  Wthb = (bf16*) (ws + 4194304);             // 2048x1024 bf16 (4MB)
    bf16*  Wc   = (bf16*) (ws + 8388608);             // 2048x2048 bf16 (8MB)
    bf16*  xr   = (bf16*) (ws + 33554432);
    bf16*  Yg   = (bf16*) (ws + 33554432);
    bf16*  xc   = (bf16*) (ws + 69730304);
    bf16*  Xb   = (bf16*) (ws + 69730304);
    bf16*  Wipb = (bf16*) (ws + 69730304 + 16777216);
    float* dtf  = (float*)(ws + 105381888);
    float* Eg   = (float*)(ws + 106430464);
    float* Sg   = (float*)d_out;

    dim3 blk(256);
    dim3 blk512(512);

    // 0) merged input casts: X (4096 blocks) + Wip (2128 blocks)
    cast2_k<<<4096 + 2128, blk, 0, stream>>>(X, Xb, Wip, Wipb, 4096);

    // 1) zxbcdt = Xb @ Wipb^T; split: z -> zbuf, xBC+dt_raw -> xr
    gemm256<bf16><<<dim3(17 * 32), blk512, 0, stream>>>(
        Xb, Wipb, zbuf, xr, M_, DIP_, DIM_, DINNER_, DINNER_, XRW_, 17);

    // 2) conv+silu + softplus(dt), merged (276 groups/row)
    conv_dt_k<<<(M_ * 276) / 256, blk, 0, stream>>>(xr, cw, cb, dtb, xc, dtf);

    // 3) chunked scan (Yg overwrites xr: dead after conv)
    chunk_intra_k<<<B_ * NC_ * NH_, blk, 0, stream>>>(
        xc, dtf, Alog, Dp, Yg, Sg, Eg);
    chunk_state_k<<<256, blk, 0, stream>>>(Sg, Eg);
    chunk_inter_k<<<B_ * NC_ * NH_, blk, 0, stream>>>(xc, Sg, dtf, Alog, Yg);

    // 4) gate + RMSNorm in place on Yg (last read of zbuf)
    gate_norm_k<<<M_, blk, 0, stream>>>(Yg, zbuf, nw);

    // 5) merged weight prep in dead zbuf region, then Wc = Wth @ Wop^T
    wprep_k<<<512 + 1024, blk, 0, stream>>>(Wop, WopT, Wth, Wthb);
    gemm_bt16<bf16><<<dim3(16, 16), blk, 0, stream>>>(
        Wthb, WopT, Wc, Wc, DINNER_, DINNER_, DIM_, DINNER_, DINNER_, DINNER_);

    // 6) HKV = ynorm @ Wc^T; f32 split HK | HV into d_out (Sg dead).
    gemm256<float><<<dim3(8 * 32), blk512, 0, stream>>>(
        Yg, Wc, out, out + (size_t)M_ * DIM_, M_, DINNER_, DINNER_, DIM_, DIM_, DIM_, 8);
}

// Round 9
// 451.537 us; speedup vs baseline: 1.0426x; 1.0426x over previous
//
#include <hip/hip_runtime.h>
#include <hip/hip_bf16.h>
#include <math.h>

#define B_       2
#define L_       4096
#define DIM_     1024
#define DINNER_  2048
#define DSTATE_  64
#define NH_      32
#define HD_      64
#define CONVDIM_ 2176
#define DIP_     4256
#define M_       (B_*L_)   // 8192
#define XRW_     2208      // xr row width: xBC raw (2176) + dt_raw (32)
#define NC_      64        // chunks (L/64)

typedef __attribute__((ext_vector_type(8))) short short8;
typedef __attribute__((ext_vector_type(4))) float floatx4;
typedef __hip_bfloat16 bf16;

__device__ __forceinline__ float bf2f(unsigned short u) {
    unsigned int v = ((unsigned int)u) << 16;
    return __builtin_bit_cast(float, v);
}
__device__ __forceinline__ unsigned short f2bf(float f) {
    unsigned int x = __builtin_bit_cast(unsigned int, f);
    unsigned int lsb = (x >> 16) & 1u;
    x += 0x7fffu + lsb;
    return (unsigned short)(x >> 16);
}
__device__ __forceinline__ void storeo(bf16* p, float v) {
    *reinterpret_cast<unsigned short*>(p) = f2bf(v);
}
__device__ __forceinline__ void storeo(float* p, float v) { *p = v; }

__device__ __forceinline__ void gl2lds16(const bf16* g, short* lds) {
    __builtin_amdgcn_global_load_lds(
        (const __attribute__((address_space(1))) void*)g,
        (__attribute__((address_space(3))) void*)lds, 16, 0, 0);
}

// ---------------------------------------------------------------------------
// Merged input cast: X (nb1 blocks) then Wip. 8 f32->bf16 per thread.
// ---------------------------------------------------------------------------
__global__ __launch_bounds__(256) void cast2_k(
    const float* __restrict__ s1, bf16* __restrict__ d1,
    const float* __restrict__ s2, bf16* __restrict__ d2, int nb1)
{
    const float* src;
    bf16* dst;
    size_t i0;
    if ((int)blockIdx.x < nb1) {
        src = s1; dst = d1;
        i0 = ((size_t)blockIdx.x * 256 + threadIdx.x) * 8;
    } else {
        src = s2; dst = d2;
        i0 = ((size_t)(blockIdx.x - nb1) * 256 + threadIdx.x) * 8;
    }
    uint4 a = *reinterpret_cast<const uint4*>(src + i0);
    uint4 b = *reinterpret_cast<const uint4*>(src + i0 + 4);
    unsigned int w0 = (unsigned int)f2bf(__builtin_bit_cast(float, a.x)) |
                      ((unsigned int)f2bf(__builtin_bit_cast(float, a.y)) << 16);
    unsigned int w1 = (unsigned int)f2bf(__builtin_bit_cast(float, a.z)) |
                      ((unsigned int)f2bf(__builtin_bit_cast(float, a.w)) << 16);
    unsigned int w2 = (unsigned int)f2bf(__builtin_bit_cast(float, b.x)) |
                      ((unsigned int)f2bf(__builtin_bit_cast(float, b.y)) << 16);
    unsigned int w3 = (unsigned int)f2bf(__builtin_bit_cast(float, b.z)) |
                      ((unsigned int)f2bf(__builtin_bit_cast(float, b.w)) << 16);
    *reinterpret_cast<uint4*>(reinterpret_cast<unsigned short*>(dst) + i0) =
        make_uint4(w0, w1, w2, w3);
}

// ---------------------------------------------------------------------------
// Merged weight prep: blocks [0,512): WopT[p,d] = bf16(Wop[d,p]) via 64x64
// LDS transpose tiles; blocks [512,1536): Wthb = bf16(Wth) elementwise.
// ---------------------------------------------------------------------------
__global__ __launch_bounds__(256) void wprep_k(
    const float* __restrict__ Wop, bf16* __restrict__ WopT,
    const float* __restrict__ Wth, bf16* __restrict__ Wthb)
{
    __shared__ unsigned short t[64][72];
    if (blockIdx.x < 512) {
        // transpose 1024x2048 -> 2048x1024
        const int R = 1024, C = 2048;
        int nct = C >> 6;
        int r0 = ((int)blockIdx.x / nct) << 6;
        int c0 = ((int)blockIdx.x % nct) << 6;
        int tr = threadIdx.x >> 2;
        int tc = (threadIdx.x & 3) << 4;
        const float* s = Wop + (size_t)(r0 + tr) * C + c0 + tc;
#pragma unroll
        for (int k = 0; k < 16; k += 4) {
            float4 v = *reinterpret_cast<const float4*>(s + k);
            t[tr][tc + k + 0] = f2bf(v.x);
            t[tr][tc + k + 1] = f2bf(v.y);
            t[tr][tc + k + 2] = f2bf(v.z);
            t[tr][tc + k + 3] = f2bf(v.w);
        }
        __syncthreads();
        unsigned short* d = (unsigned short*)WopT + (size_t)(c0 + tr) * R + r0 + tc;
        unsigned int ww[8];
#pragma unroll
        for (int q = 0; q < 8; q++)
            ww[q] = (unsigned int)t[tc + 2*q][tr] | ((unsigned int)t[tc + 2*q + 1][tr] << 16);
        *reinterpret_cast<uint4*>(d)     = make_uint4(ww[0], ww[1], ww[2], ww[3]);
        *reinterpret_cast<uint4*>(d + 8) = make_uint4(ww[4], ww[5], ww[6], ww[7]);
    } else {
        size_t i0 = ((size_t)(blockIdx.x - 512) * 256 + threadIdx.x) * 8;
        uint4 a = *reinterpret_cast<const uint4*>(Wth + i0);
        uint4 b = *reinterpret_cast<const uint4*>(Wth + i0 + 4);
        unsigned int w0 = (unsigned int)f2bf(__builtin_bit_cast(float, a.x)) |
                          ((unsigned int)f2bf(__builtin_bit_cast(float, a.y)) << 16);
        unsigned int w1 = (unsigned int)f2bf(__builtin_bit_cast(float, a.z)) |
                          ((unsigned int)f2bf(__builtin_bit_cast(float, a.w)) << 16);
        unsigned int w2 = (unsigned int)f2bf(__builtin_bit_cast(float, b.x)) |
                          ((unsigned int)f2bf(__builtin_bit_cast(float, b.y)) << 16);
        unsigned int w3 = (unsigned int)f2bf(__builtin_bit_cast(float, b.z)) |
                          ((unsigned int)f2bf(__builtin_bit_cast(float, b.w)) << 16);
        *reinterpret_cast<uint4*>(reinterpret_cast<unsigned short*>(Wthb) + i0) =
            make_uint4(w0, w1, w2, w3);
    }
}

// ---------------------------------------------------------------------------
// bf16 GEMM, m97 structure, 128x128 tile (proven baseline kernel).
// Used for the small Wc = Wth @ Wop^T weight-product GEMM (256 blocks).
// ---------------------------------------------------------------------------
template <typename TO>
__global__ __launch_bounds__(256) void gemm_bt16(
    const bf16* __restrict__ A, const bf16* __restrict__ W,
    TO* __restrict__ outA, TO* __restrict__ outB,
    int M, int N, int K, int split, int strideA, int strideB)
{
    __shared__ short As[128*64];
    __shared__ short Ws[128*64];
    const int tid  = threadIdx.x;
    const int m0   = blockIdx.y * 128;
    const int n0   = blockIdx.x * 128;
    const int wave = tid >> 6;
    const int lane = tid & 63;
    const int wm   = (wave >> 1) * 64;
    const int wn   = (wave & 1) * 64;
    const int ln   = lane & 15;
    const int quad = lane >> 4;
    const int lr   = lane >> 3;
    const int lc   = (lane & 7) * 8;

    floatx4 acc[4][4];
#pragma unroll
    for (int i = 0; i < 4; i++)
#pragma unroll
        for (int j = 0; j < 4; j++) acc[i][j] = (floatx4){0.f, 0.f, 0.f, 0.f};

    for (int k0 = 0; k0 < K; k0 += 64) {
#pragma unroll
        for (int it = 0; it < 4; it++) {
            int ig = wave * 4 + it;
            gl2lds16(A + (size_t)(m0 + ig * 8 + lr) * K + k0 + lc, &As[ig * 512]);
            gl2lds16(W + (size_t)(n0 + ig * 8 + lr) * K + k0 + lc, &Ws[ig * 512]);
        }
        __syncthreads();
#pragma unroll
        for (int kk = 0; kk < 64; kk += 32) {
            short8 af[4], bfv[4];
#pragma unroll
            for (int i = 0; i < 4; i++)
                af[i] = *reinterpret_cast<const short8*>(&As[(wm + i * 16 + ln) * 64 + kk + quad * 8]);
#pragma unroll
            for (int j = 0; j < 4; j++)
                bfv[j] = *reinterpret_cast<const short8*>(&Ws[(wn + j * 16 + ln) * 64 + kk + quad * 8]);
#pragma unroll
            for (int i = 0; i < 4; i++)
#pragma unroll
                for (int j = 0; j < 4; j++)
                    acc[i][j] = __builtin_amdgcn_mfma_f32_16x16x32_bf16(af[i], bfv[j], acc[i][j], 0, 0, 0);
        }
        __syncthreads();
    }

#pragma unroll
    for (int i = 0; i < 4; i++)
#pragma unroll
        for (int j = 0; j < 4; j++)
#pragma unroll
            for (int r = 0; r < 4; r++) {
                int grow = m0 + wm + i * 16 + quad * 4 + r;
                int gcol = n0 + wn + j * 16 + ln;
                if (gcol < N) {
                    if (gcol < split)
                        storeo(outA + (size_t)grow * strideA + gcol, acc[i][j][r]);
                    else
                        storeo(outB + (size_t)grow * strideB + (gcol - split), acc[i][j][r]);
                }
            }
}

// ---------------------------------------------------------------------------
// bf16 GEMM, 256x256 tile, single-barrier-per-K-tile schedule (R3/R5/R7
// proven, best measured: 99 us on gemm1). 512 threads = 8 waves 2(M)x4(N);
// per-wave output 128x64. LDS 128 KiB double-buffered; 3-bit XOR swizzle
// ((row&7)<<4) via inverse-swizzled global source + swizzled ds_read
// (0 bank conflicts). Per K-tile: ds_reads in consumption order, 8
// global_load_lds prefetch, 64-MFMA run under setprio; {vmcnt(0);
// s_barrier} at tile end orders double-buffer hazards globally.
// ---------------------------------------------------------------------------
template <typename TO>
__global__ __launch_bounds__(512, 2) void gemm256(
    const bf16* __restrict__ Ag, const bf16* __restrict__ Wg,
    TO* __restrict__ outA, TO* __restrict__ outB,
    int M, int N, int K, int split, int strideA, int strideB, int nbx)
{
    __shared__ short lds[65536];   // 128 KiB: A at [0,32768), B at [32768,65536)

    const int tid  = threadIdx.x;
    const int wave = tid >> 6;
    const int lane = tid & 63;
    const int ln   = lane & 15;
    const int quad = lane >> 4;
    const int wr   = wave >> 2;    // 0..1 (M)
    const int wc   = wave & 3;     // 0..3 (N)
    const int bh   = wc >> 1;      // B half this wave reads
    const int wcl  = wc & 1;
    const int xorv = (ln & 7) << 4;   // read-side swizzle (3 row bits)

    // XCD-aware bijective block swizzle (nwg % 8 == 0 for all our launches)
    int nwg  = gridDim.x;
    int orig = blockIdx.x;
    int wg   = ((nwg & 7) == 0) ? ((orig & 7) * (nwg >> 3) + (orig >> 3)) : orig;
    const int bx = wg % nbx;
    const int by = wg / nbx;
    const int m0 = by * 256;
    const int n0 = bx * 256;

    // staging: thread covers linear (physical) 16B chunks of each 16KB
    // half-tile; fetch the global element at the swizzle-inverse (logical)
    // offset so that swizzled reads see a consistent layout.
    int lo0 = tid * 16;
    int lo1 = 8192 + tid * 16;
    int so0 = lo0 ^ (((lo0 >> 7) & 7) << 4);
    int so1 = lo1 ^ (((lo1 >> 7) & 7) << 4);
    const int srow0 = so0 >> 7, scol0 = (so0 & 127) >> 1;
    const int srow1 = so1 >> 7, scol1 = (so1 & 127) >> 1;

#define STG_A(bufb, h, kc) do {                                               \
    short* dst_ = &lds[((bufb)*2 + (h)) * 8192 + wave * 512];                 \
    gl2lds16(Ag + (size_t)(m0 + (h)*128 + srow0) * K + (kc) + scol0, dst_);   \
    gl2lds16(Ag + (size_t)(m0 + (h)*128 + srow1) * K + (kc) + scol1, dst_ + 4096); \
} while (0)
#define STG_B(bufb, h, kc) do {                                               \
    short* dst_ = &lds[32768 + ((bufb)*2 + (h)) * 8192 + wave * 512];         \
    gl2lds16(Wg + (size_t)(n0 + (h)*128 + srow0) * K + (kc) + scol0, dst_);   \
    gl2lds16(Wg + (size_t)(n0 + (h)*128 + srow1) * K + (kc) + scol1, dst_ + 4096); \
} while (0)

#define RD_A(qi) do {                                                         \
    const char* Ab_ = (const char*)&lds[(cur*2 + wr) * 8192];                 \
    _Pragma("unroll") for (int i = 0; i < 4; i++)                             \
    _Pragma("unroll") for (int ks = 0; ks < 2; ks++)                          \
        af[i][ks] = *reinterpret_cast<const short8*>(                         \
            Ab_ + ((((qi)*64 + i*16 + ln)*128 + ks*64 + quad*16) ^ xorv));    \
} while (0)
#define RD_B(qj, BV) do {                                                     \
    const char* Bb_ = (const char*)&lds[32768 + (cur*2 + bh) * 8192];         \
    _Pragma("unroll") for (int j = 0; j < 2; j++)                             \
    _Pragma("unroll") for (int ks = 0; ks < 2; ks++)                          \
        BV[j][ks] = *reinterpret_cast<const short8*>(                         \
            Bb_ + (((wcl*64 + (qj)*32 + j*16 + ln)*128 + ks*64 + quad*16) ^ xorv)); \
} while (0)

#define MMA(qi, qj, BV) do {                                                  \
    _Pragma("unroll") for (int i = 0; i < 4; i++)                             \
    _Pragma("unroll") for (int j = 0; j < 2; j++)                             \
    _Pragma("unroll") for (int ks = 0; ks < 2; ks++)                          \
        acc[(qi)*4+i][(qj)*2+j] = __builtin_amdgcn_mfma_f32_16x16x32_bf16(    \
            af[i][ks], BV[j][ks], acc[(qi)*4+i][(qj)*2+j], 0, 0, 0);          \
} while (0)

    floatx4 acc[8][4];
#pragma unroll
    for (int i = 0; i < 8; i++)
#pragma unroll
        for (int j = 0; j < 4; j++) acc[i][j] = (floatx4){0.f, 0.f, 0.f, 0.f};

    const int NT = K >> 6;

    // prologue: stage tile 0 fully, drain, barrier
    STG_A(0, 0, 0); STG_A(0, 1, 0);
    STG_B(0, 0, 0); STG_B(0, 1, 0);
    asm volatile("s_waitcnt vmcnt(0)" ::: "memory");
    __builtin_amdgcn_s_barrier();
    __builtin_amdgcn_sched_barrier(0);

    short8 af[4][2], bf0[2][2], bf1[2][2];

    for (int t = 0; t < NT; ++t) {
        const int cur = t & 1, nxt = cur ^ 1;
        const int kc  = (t + 1) << 6;
        const bool pf = (t + 1 < NT);

        // fragment reads in consumption order
        RD_A(0);          // af  <- A quadrant 0   (8 b128)
        RD_B(0, bf0);     // bf0 <- B quadrant 0   (4 b128)
        RD_B(1, bf1);     // bf1 <- B quadrant 1   (4 b128)

        // prefetch tile t+1 (lands ~900 cyc later, drained at tile end)
        if (pf) {
            STG_A(nxt, 0, kc); STG_A(nxt, 1, kc);
            STG_B(nxt, 0, kc); STG_B(nxt, 1, kc);
        }

        // 64-MFMA run; lgkmcnt pipelines the read backlog underneath
        __builtin_amdgcn_s_setprio(1);
        MMA(0, 0, bf0);
        MMA(0, 1, bf1);
        RD_A(1);          // af <- A quadrant 1 (after both q0 consumers)
        MMA(1, 1, bf1);
        MMA(1, 0, bf0);
        __builtin_amdgcn_s_setprio(0);

        if (pf) { asm volatile("s_waitcnt vmcnt(0)" ::: "memory"); }
        __builtin_amdgcn_s_barrier();
        __builtin_amdgcn_sched_barrier(0);
    }

#undef STG_A
#undef STG_B
#undef RD_A
#undef RD_B
#undef MMA

    // epilogue: split store
#pragma unroll
    for (int qi = 0; qi < 2; qi++)
#pragma unroll
    for (int i = 0; i < 4; i++)
#pragma unroll
    for (int qj = 0; qj < 2; qj++)
#pragma unroll
    for (int j = 0; j < 2; j++)
#pragma unroll
    for (int r = 0; r < 4; r++) {
        int grow = m0 + wr*128 + qi*64 + i*16 + quad*4 + r;
        int gcol = n0 + wc*64 + qj*32 + j*16 + ln;
        float v = acc[qi*4+i][qj*2+j][r];
        if (gcol < N) {
            if (gcol < split)
                storeo(outA + (size_t)grow * strideA + gcol, v);
            else
                storeo(outB + (size_t)grow * strideB + (gcol - split), v);
        }
    }
}

// ---------------------------------------------------------------------------
// Conv+bias+silu over 2176 xBC channels PLUS softplus(dt) — merged kernel.
// 276 groups of 8 per row: groups [0,272) conv, [272,276) dt.
// Grid: M*276/256 = 8832.
// ---------------------------------------------------------------------------
__global__ __launch_bounds__(256) void conv_dt_k(
    const bf16* __restrict__ xr, const float* __restrict__ cw,
    const float* __restrict__ cb, const float* __restrict__ dtb,
    bf16* __restrict__ xc, float* __restrict__ dtf)
{
    int idx = blockIdx.x * 256 + threadIdx.x;
    int row = idx / 276;
    int g   = idx - row * 276;
    const unsigned short* xru = (const unsigned short*)xr;

    if (g >= 272) {
        int h0 = (g - 272) * 8;
        uint4 rv = *reinterpret_cast<const uint4*>(xru + (size_t)row * XRW_ + 2176 + h0);
        const unsigned int* w = &rv.x;
        float o[8];
#pragma unroll
        for (int k = 0; k < 8; k++) {
            unsigned short u = (k & 1) ? (unsigned short)(w[k >> 1] >> 16)
                                       : (unsigned short)(w[k >> 1] & 0xffffu);
            float v = bf2f(u) + dtb[h0 + k];
            o[k] = fmaxf(v, 0.f) + log1pf(__expf(-fabsf(v)));
        }
        *reinterpret_cast<float4*>(&dtf[(size_t)row * NH_ + h0]) =
            make_float4(o[0], o[1], o[2], o[3]);
        *reinterpret_cast<float4*>(&dtf[(size_t)row * NH_ + h0 + 4]) =
            make_float4(o[4], o[5], o[6], o[7]);
        return;
    }

    int ch0 = g * 8;
    int t   = row & (L_ - 1);
    uint4 rv[4];
#pragma unroll
    for (int j = 0; j < 4; j++) {
        rv[j] = make_uint4(0u, 0u, 0u, 0u);
        if (t + j - 3 >= 0)
            rv[j] = *reinterpret_cast<const uint4*>(xru + (size_t)(row + j - 3) * XRW_ + ch0);
    }
    unsigned int ow[4];
#pragma unroll
    for (int pair = 0; pair < 4; pair++) {
        unsigned short o2[2];
#pragma unroll
        for (int k = 0; k < 2; k++) {
            int cc = pair * 2 + k;
            float a = cb[ch0 + cc];
#pragma unroll
            for (int j = 0; j < 4; j++) {
                unsigned int w32 = (&rv[j].x)[cc >> 1];
                unsigned short u = (cc & 1) ? (unsigned short)(w32 >> 16)
                                            : (unsigned short)(w32 & 0xffffu);
                a = fmaf(bf2f(u), cw[(ch0 + cc) * 4 + j], a);
            }
            o2[k] = f2bf(a / (1.f + __expf(-a)));
        }
        ow[pair] = (unsigned int)o2[0] | ((unsigned int)o2[1] << 16);
    }
    *reinterpret_cast<uint4*>((unsigned short*)xc + (size_t)row * CONVDIM_ + ch0) =
        make_uint4(ow[0], ow[1], ow[2], ow[3]);
}

// ---------------------------------------------------------------------------
// Pass A (slim): per (b,chunk,h): stage pre-activated x/B/C, 3 MFMA GEMMs.
// blockIdx.x = ((b*64+c)*32+h). Wave-parallel prefix scan for cums.
// Sg is now bf16 (intra stores rounded S; state/inter read bf16).
// ---------------------------------------------------------------------------
__global__ __launch_bounds__(256) void chunk_intra_k(
    const bf16* __restrict__ xc, const float* __restrict__ dtf,
    const float* __restrict__ A_log, const float* __restrict__ Dp,
    bf16* __restrict__ Yg, unsigned short* __restrict__ Sg, float* __restrict__ Eg)
{
    __shared__ short Bst[64*72];
    __shared__ short Cst[64*72];
    __shared__ short xsM[64*72];   // x staging, then reused as masked M
    __shared__ short xT [64*72];
    __shared__ short BwT[64*72];
    __shared__ float dts[64], cums[64], wS[64];

    const int tid  = threadIdx.x;
    const int bid  = blockIdx.x;
    const int h    = bid & 31;
    const int bc   = bid >> 5;
    const int c    = bc & 63;
    const int b    = bc >> 6;
    const int xch0 = h * 64;
    const unsigned short* xcu = (const unsigned short*)xc;

    const float Ah = -__expf(A_log[h]);
    const float Dh = Dp[h];

    // stage B / C / x tiles (rows s = 0..63)
    for (int q = tid; q < 1536; q += 256) {
        int sel = q >> 9;              // 0:B 1:C 2:x
        int qq  = q & 511;
        int r = qq >> 3, c8 = (qq & 7) * 8;
        size_t ro = (size_t)(b * L_ + c * 64 + r) * CONVDIM_;
        if (sel == 0)
            *reinterpret_cast<uint4*>(&Bst[r*72 + c8]) =
                *reinterpret_cast<const uint4*>(xcu + ro + 2048 + c8);
        else if (sel == 1)
            *reinterpret_cast<uint4*>(&Cst[r*72 + c8]) =
                *reinterpret_cast<const uint4*>(xcu + ro + 2112 + c8);
        else
            *reinterpret_cast<uint4*>(&xsM[r*72 + c8]) =
                *reinterpret_cast<const uint4*>(xcu + ro + xch0 + c8);
    }
    if (tid < 64) dts[tid] = dtf[(size_t)(b * L_ + c * 64 + tid) * NH_ + h];
    __syncthreads();

    // wave-parallel inclusive prefix scan of dts*Ah (wave 0, 6 shfl steps)
    if (tid < 64) {
        float v = dts[tid] * Ah;
#pragma unroll
        for (int o = 1; o < 64; o <<= 1) {
            float u = __shfl_up(v, o, 64);
            if (tid >= o) v += u;
        }
        cums[tid] = v;
    }
    __syncthreads();
    if (tid < 64) wS[tid] = __expf(cums[63] - cums[tid]) * dts[tid];
    if (tid == 0) Eg[bid] = __expf(cums[63]);
    __syncthreads();

    // transposes: xT[p][s] = x[s][p]; BwT[n][s] = B[s][n]*wS[s]
    for (int q = tid; q < 4096; q += 256) {
        int s = q & 63, ch = q >> 6;
        xT [ch*72 + s] = xsM[s*72 + ch];
        BwT[ch*72 + s] = (short)f2bf(bf2f((unsigned short)Bst[s*72 + ch]) * wS[s]);
    }
    __syncthreads();

    const int wave = tid >> 6, lane = tid & 63;
    const int ln = lane & 15, quad = lane >> 4;
    const int wm = (wave >> 1) * 32, wn = (wave & 1) * 32;

    // --- G = C · B^T ---
    floatx4 accG[2][2];
#pragma unroll
    for (int i = 0; i < 2; i++)
#pragma unroll
        for (int j = 0; j < 2; j++) accG[i][j] = (floatx4){0.f,0.f,0.f,0.f};
#pragma unroll
    for (int kk = 0; kk < 64; kk += 32) {
        short8 af[2], bfv[2];
#pragma unroll
        for (int i = 0; i < 2; i++)
            af[i] = *reinterpret_cast<const short8*>(&Cst[(wm + i*16 + ln)*72 + kk + quad*8]);
#pragma unroll
        for (int j = 0; j < 2; j++)
            bfv[j] = *reinterpret_cast<const short8*>(&Bst[(wn + j*16 + ln)*72 + kk + quad*8]);
#pragma unroll
        for (int i = 0; i < 2; i++)
#pragma unroll
            for (int j = 0; j < 2; j++)
                accG[i][j] = __builtin_amdgcn_mfma_f32_16x16x32_bf16(af[i], bfv[j], accG[i][j], 0,0,0);
    }
    __syncthreads();   // all xsM staging reads done -> safe to overwrite
#pragma unroll
    for (int i = 0; i < 2; i++)
#pragma unroll
        for (int j = 0; j < 2; j++)
#pragma unroll
            for (int r = 0; r < 4; r++) {
                int t = wm + i*16 + quad*4 + r;
                int s = wn + j*16 + ln;
                float v = (s <= t) ? __expf(cums[t] - cums[s]) * dts[s] * accG[i][j][r] : 0.f;
                xsM[t*72 + s] = (short)f2bf(v);
            }
    __syncthreads();

    // --- Yintra = M · xT^T + D*x ---
    floatx4 accY[2][2];
#pragma unroll
    for (int i = 0; i < 2; i++)
#pragma unroll
        for (int j = 0; j < 2; j++) accY[i][j] = (floatx4){0.f,0.f,0.f,0.f};
#pragma unroll
    for (int kk = 0; kk < 64; kk += 32) {
        short8 af[2], bfv[2];
#pragma unroll
        for (int i = 0; i < 2; i++)
            af[i] = *reinterpret_cast<const short8*>(&xsM[(wm + i*16 + ln)*72 + kk + quad*8]);
#pragma unroll
        for (int j = 0; j < 2; j++)
            bfv[j] = *reinterpret_cast<const short8*>(&xT[(wn + j*16 + ln)*72 + kk + quad*8]);
#pragma unroll
        for (int i = 0; i < 2; i++)
#pragma unroll
            for (int j = 0; j < 2; j++)
                accY[i][j] = __builtin_amdgcn_mfma_f32_16x16x32_bf16(af[i], bfv[j], accY[i][j], 0,0,0);
    }
    unsigned short* Yu = (unsigned short*)Yg;
#pragma unroll
    for (int i = 0; i < 2; i++)
#pragma unroll
        for (int j = 0; j < 2; j++)
#pragma unroll
            for (int r = 0; r < 4; r++) {
                int t = wm + i*16 + quad*4 + r;
                int p = wn + j*16 + ln;
                float yv = accY[i][j][r] + Dh * bf2f((unsigned short)xT[p*72 + t]);
                Yu[(size_t)(b*L_ + c*64 + t)*DINNER_ + xch0 + p] = f2bf(yv);
            }

    // --- S^T = xT · BwT^T (stored bf16) ---
    floatx4 accS[2][2];
#pragma unroll
    for (int i = 0; i < 2; i++)
#pragma unroll
        for (int j = 0; j < 2; j++) accS[i][j] = (floatx4){0.f,0.f,0.f,0.f};
#pragma unroll
    for (int kk = 0; kk < 64; kk += 32) {
        short8 af[2], bfv[2];
#pragma unroll
        for (int i = 0; i < 2; i++)
            af[i] = *reinterpret_cast<const short8*>(&xT[(wm + i*16 + ln)*72 + kk + quad*8]);
#pragma unroll
        for (int j = 0; j < 2; j++)
            bfv[j] = *reinterpret_cast<const short8*>(&BwT[(wn + j*16 + ln)*72 + kk + quad*8]);
#pragma unroll
        for (int i = 0; i < 2; i++)
#pragma unroll
            for (int j = 0; j < 2; j++)
                accS[i][j] = __builtin_amdgcn_mfma_f32_16x16x32_bf16(af[i], bfv[j], accS[i][j], 0,0,0);
    }
#pragma unroll
    for (int i = 0; i < 2; i++)
#pragma unroll
        for (int j = 0; j < 2; j++)
#pragma unroll
            for (int r = 0; r < 4; r++) {
                int p = wm + i*16 + quad*4 + r;
                int n = wn + j*16 + ln;
                Sg[(size_t)bid * 4096 + p*64 + n] = f2bf(accS[i][j][r]);
            }
}

// ---------------------------------------------------------------------------
// Pass B: prefix over chunks. Sg bf16 (run kept f32 in registers).
// Thread owns 4 consecutive e (uint2 = 4 bf16). Grid 256 blocks.
// ---------------------------------------------------------------------------
__global__ __launch_bounds__(256) void chunk_state_k(
    unsigned short* __restrict__ Sg, const float* __restrict__ Eg)
{
    int g  = blockIdx.x * 256 + threadIdx.x;  // 65536 threads
    int bh = g >> 10;                          // 1024 threads per (b,h)
    int b  = bh >> 5, h = bh & 31;
    int e  = (g & 1023) * 4;
    float4 run = make_float4(0.f, 0.f, 0.f, 0.f);
    for (int c = 0; c < NC_; c++) {
        int bid = (b * 64 + c) * 32 + h;
        size_t idx = (size_t)bid * 4096 + e;
        uint2 sv = *reinterpret_cast<uint2*>(&Sg[idx]);
        float s0 = bf2f((unsigned short)(sv.x & 0xffffu));
        float s1 = bf2f((unsigned short)(sv.x >> 16));
        float s2 = bf2f((unsigned short)(sv.y & 0xffffu));
        float s3 = bf2f((unsigned short)(sv.y >> 16));
        float  E = Eg[bid];
        unsigned int o0 = (unsigned int)f2bf(run.x) | ((unsigned int)f2bf(run.y) << 16);
        unsigned int o1 = (unsigned int)f2bf(run.z) | ((unsigned int)f2bf(run.w) << 16);
        *reinterpret_cast<uint2*>(&Sg[idx]) = make_uint2(o0, o1);
        run.x = run.x * E + s0;
        run.y = run.y * E + s1;
        run.z = run.z * E + s2;
        run.w = run.w * E + s3;
    }
}

// ---------------------------------------------------------------------------
// Pass C: Y += e^{cum[t]} * C·hprev^T. Sg bf16 -> direct uint4 LDS staging.
// ---------------------------------------------------------------------------
__global__ __launch_bounds__(256) void chunk_inter_k(
    const bf16* __restrict__ xc, const unsigned short* __restrict__ Sg,
    const float* __restrict__ dtf, const float* __restrict__ A_log,
    bf16* __restrict__ Yg)
{
    __shared__ short Cst[64*72];
    __shared__ short hpT[64*72];
    __shared__ float dts[64], wcumL[64];

    const int tid = threadIdx.x;
    const int bid = blockIdx.x;
    const int h   = bid & 31;
    const int bc  = bid >> 5;
    const int c   = bc & 63;
    const int b   = bc >> 6;
    const unsigned short* xcu = (const unsigned short*)xc;

    const float Ah = -__expf(A_log[h]);

    for (int q = tid; q < 512; q += 256) {
        int r = q >> 3, c8 = (q & 7) * 8;
        *reinterpret_cast<uint4*>(&Cst[r*72 + c8]) =
            *reinterpret_cast<const uint4*>(xcu + (size_t)(b*L_ + c*64 + r)*CONVDIM_ + 2112 + c8);
    }
    for (int q = tid; q < 512; q += 256) {
        int p = q >> 3, n8 = (q & 7) * 8;
        *reinterpret_cast<uint4*>(&hpT[p*72 + n8]) =
            *reinterpret_cast<const uint4*>(&Sg[(size_t)bid * 4096 + p*64 + n8]);
    }
    if (tid < 64) dts[tid] = dtf[(size_t)(b*L_ + c*64 + tid) * NH_ + h];
    __syncthreads();
    if (tid < 64) {
        float v = dts[tid] * Ah;
#pragma unroll
        for (int o = 1; o < 64; o <<= 1) {
            float u = __shfl_up(v, o, 64);
            if (tid >= o) v += u;
        }
        wcumL[tid] = __expf(v);
    }
    __syncthreads();

    const int wave = tid >> 6, lane = tid & 63;
    const int ln = lane & 15, quad = lane >> 4;
    const int wm = (wave >> 1) * 32, wn = (wave & 1) * 32;

    floatx4 acc[2][2];
#pragma unroll
    for (int i = 0; i < 2; i++)
#pragma unroll
        for (int j = 0; j < 2; j++) acc[i][j] = (floatx4){0.f,0.f,0.f,0.f};
#pragma unroll
    for (int kk = 0; kk < 64; kk += 32) {
        short8 af[2], bfv[2];
#pragma unroll
        for (int i = 0; i < 2; i++)
            af[i] = *reinterpret_cast<const short8*>(&Cst[(wm + i*16 + ln)*72 + kk + quad*8]);
#pragma unroll
        for (int j = 0; j < 2; j++)
            bfv[j] = *reinterpret_cast<const short8*>(&hpT[(wn + j*16 + ln)*72 + kk + quad*8]);
#pragma unroll
        for (int i = 0; i < 2; i++)
#pragma unroll
            for (int j = 0; j < 2; j++)
                acc[i][j] = __builtin_amdgcn_mfma_f32_16x16x32_bf16(af[i], bfv[j], acc[i][j], 0,0,0);
    }
    unsigned short* Yu = (unsigned short*)Yg;
#pragma unroll
    for (int i = 0; i < 2; i++)
#pragma unroll
        for (int j = 0; j < 2; j++)
#pragma unroll
            for (int r = 0; r < 4; r++) {
                int t = wm + i*16 + quad*4 + r;
                int p = wn + j*16 + ln;
                size_t idx = (size_t)(b*L_ + c*64 + t)*DINNER_ + h*64 + p;
                float yv = bf2f(Yu[idx]) + wcumL[t] * acc[i][j][r];
                Yu[idx] = f2bf(yv);
            }
}

// ---------------------------------------------------------------------------
// gate + RMSNorm (unchanged).
// ---------------------------------------------------------------------------
__global__ __launch_bounds__(256) void gate_norm_k(
    bf16* __restrict__ y, const bf16* __restrict__ zbuf, const float* __restrict__ nw)
{
    __shared__ float red[4];
    int row = blockIdx.x;
    int tid = threadIdx.x;
    unsigned short* yy = (unsigned short*)y;
    const unsigned short* zz = (const unsigned short*)zbuf;

    uint4 yv = *reinterpret_cast<uint4*>(&yy[(size_t)row * DINNER_ + tid * 8]);
    uint4 zv = *reinterpret_cast<const uint4*>(&zz[(size_t)row * DINNER_ + tid * 8]);
    unsigned int yw[4] = {yv.x, yv.y, yv.z, yv.w};
    unsigned int zw[4] = {zv.x, zv.y, zv.z, zv.w};
    float g[8];
    float ss = 0.f;
#pragma unroll
    for (int q = 0; q < 4; q++) {
        float y0 = bf2f((unsigned short)(yw[q] & 0xffffu)), y1 = bf2f((unsigned short)(yw[q] >> 16));
        float z0 = bf2f((unsigned short)(zw[q] & 0xffffu)), z1 = bf2f((unsigned short)(zw[q] >> 16));
        float g0 = y0 * (z0 / (1.f + __expf(-z0)));
        float g1 = y1 * (z1 / (1.f + __expf(-z1)));
        g[q * 2] = g0; g[q * 2 + 1] = g1;
        ss += g0 * g0 + g1 * g1;
    }
#pragma unroll
    for (int o = 1; o < 64; o <<= 1) ss += __shfl_xor(ss, o);
    if ((tid & 63) == 0) red[tid >> 6] = ss;
    __syncthreads();
    float tot = red[0] + red[1] + red[2] + red[3];
    float rinv = rsqrtf(tot * (1.f / DINNER_) + 1e-5f);

    unsigned int ow[4];
#pragma unroll
    for (int q = 0; q < 4; q++) {
        float w0 = nw[tid * 8 + q * 2];
        float w1 = nw[tid * 8 + q * 2 + 1];
        unsigned short o0 = f2bf(g[q * 2] * rinv * w0);
        unsigned short o1 = f2bf(g[q * 2 + 1] * rinv * w1);
        ow[q] = (unsigned int)o0 | ((unsigned int)o1 << 16);
    }
    *reinterpret_cast<uint4*>(&yy[(size_t)row * DINNER_ + tid * 8]) =
        make_uint4(ow[0], ow[1], ow[2], ow[3]);
}

// ---------------------------------------------------------------------------

extern "C" void kernel_launch(void* const* d_in, const int* in_sizes, int n_in,
                              void* d_out, int out_size, void* d_ws, size_t ws_size,
                              hipStream_t stream)
{
    const float* X    = (const float*)d_in[0];
    const float* Wip  = (const float*)d_in[1];
    const float* cw   = (const float*)d_in[2];
    const float* cb   = (const float*)d_in[3];
    const float* dtb  = (const float*)d_in[4];
    const float* Alog = (const float*)d_in[5];
    const float* Dp   = (const float*)d_in[6];
    const float* nw   = (const float*)d_in[7];
    const float* Wop  = (const float*)d_in[8];
    const float* Wth  = (const float*)d_in[9];
    float* out = (float*)d_out;

    // ws layout (peak 106,446,848 B):
    //   [0, 33554432)          zbuf (gemm1->gate); after gate: WopT (4MB) |
    //                          Wthb (4MB) | Wc (8MB) in the dead zbuf region
    //   [33554432, 69730304)   xr (gemm1->conv_dt); then Yg
    //   [69730304, 105381888)  xc (conv_dt->chunk_inter); Xb/Wipb alias
    //                          pre-gemm1
    //   [105381888, 106430464) dtf M x 32 f32
    //   [106430464, 106446848) Eg 4096 f32
    // Sg (bf16, 32MB) lives in d_out (dead before HKV gemm overwrites d_out).
    char* ws = (char*)d_ws;
    bf16*  zbuf = (bf16*) (ws);
    bf16*  WopT = (bf16*) (ws);                       // 2048x1024 bf16 (4MB)
    bf16*  Wthb = (bf16*) (ws + 4194304);             // 2048x1024 bf16 (4MB)
    bf16*  Wc   = (bf16*) (ws + 8388608);             // 2048x2048 bf16 (8MB)
    bf16*  xr   = (bf16*) (ws + 33554432);
    bf16*  Yg   = (bf16*) (ws + 33554432);
    bf16*  xc   = (bf16*) (ws + 69730304);
    bf16*  Xb   = (bf16*) (ws + 69730304);
    bf16*  Wipb = (bf16*) (ws + 69730304 + 16777216);
    float* dtf  = (float*)(ws + 105381888);
    float* Eg   = (float*)(ws + 106430464);
    unsigned short* Sg = (unsigned short*)d_out;

    dim3 blk(256);
    dim3 blk512(512);

    // 0) merged input casts: X (4096 blocks) + Wip (2128 blocks)
    cast2_k<<<4096 + 2128, blk, 0, stream>>>(X, Xb, Wip, Wipb, 4096);

    // 1) zxbcdt = Xb @ Wipb^T; split: z -> zbuf, xBC+dt_raw -> xr
    gemm256<bf16><<<dim3(17 * 32), blk512, 0, stream>>>(
        Xb, Wipb, zbuf, xr, M_, DIP_, DIM_, DINNER_, DINNER_, XRW_, 17);

    // 2) conv+silu + softplus(dt), merged (276 groups/row)
    conv_dt_k<<<(M_ * 276) / 256, blk, 0, stream>>>(xr, cw, cb, dtb, xc, dtf);

    // 3) chunked scan (Yg overwrites xr: dead after conv); Sg bf16 in d_out
    chunk_intra_k<<<B_ * NC_ * NH_, blk, 0, stream>>>(
        xc, dtf, Alog, Dp, Yg, Sg, Eg);
    chunk_state_k<<<256, blk, 0, stream>>>(Sg, Eg);
    chunk_inter_k<<<B_ * NC_ * NH_, blk, 0, stream>>>(xc, Sg, dtf, Alog, Yg);

    // 4) gate + RMSNorm in place on Yg (last read of zbuf)
    gate_norm_k<<<M_, blk, 0, stream>>>(Yg, zbuf, nw);

    // 5) merged weight prep in dead zbuf region, then Wc = Wth @ Wop^T
    wprep_k<<<512 + 1024, blk, 0, stream>>>(Wop, WopT, Wth, Wthb);
    gemm_bt16<bf16><<<dim3(16, 16), blk, 0, stream>>>(
        Wthb, WopT, Wc, Wc, DINNER_, DINNER_, DIM_, DINNER_, DINNER_, DINNER_);

    // 6) HKV = ynorm @ Wc^T; f32 split HK | HV into d_out (Sg dead).
    gemm256<float><<<dim3(8 * 32), blk512, 0, stream>>>(
        Yg, Wc, out, out + (size_t)M_ * DIM_, M_, DINNER_, DINNER_, DIM_, DIM_, DIM_, 8);
}